// Round 3
// baseline (656.550 us; speedup 1.0000x reference)
//
#include <hip/hip_runtime.h>
#include <cstdint>

#define EPS 1e-5f
constexpr int B = 4, C = 512, HW = 16384, K = 32;

typedef __bf16 bf16x8 __attribute__((ext_vector_type(8)));
typedef float  floatx4 __attribute__((ext_vector_type(4)));
typedef unsigned int u32;

__device__ __forceinline__ void load_lds16(const void* g, void* l) {
    __builtin_amdgcn_global_load_lds((const __attribute__((address_space(1))) u32*)g,
                                     (__attribute__((address_space(3))) u32*)l,
                                     16, 0, 0);
}

// ---------------------------------------------------------------------------
// workspace byte offsets
constexpr size_t Z_OFF     = 0;            // z bf16 [b][n][c]    67,108,864
constexpr size_t WBB_OFF   = 67108864;     // W bf16 frag-swizzled   524,288
constexpr size_t CWB_OFF   = 67633152;     // cw bf16 [k][c]          32,768
constexpr size_t X2_OFF    = 67665920;     // fp32 [b*HW]            262,144
constexpr size_t C2_OFF    = 67928064;     // fp32 [K]
constexpr size_t ASUM_OFF  = 67928192;     // fp32 [B*K]
constexpr size_t PART_OFF  = 67928704;     // fp32 [B][128][K][C] 33,554,432
constexpr size_t AGG_OFF   = 101483136;    // fp32 [B][K][C]         262,144
constexpr size_t GAMMA_OFF = 101745280;    // fp32 [B][C]              8,192
constexpr size_t XT_OFF    = 101753472;    // bf16 [b][8][16384][64] 67,108,864
constexpr size_t XT_BYTES  = (size_t)B * 8 * 16384 * 64 * 2;
constexpr size_t WS_NEEDED = XT_OFF + XT_BYTES;   // 168,862,336

// ---------------------------------------------------------------------------
// prep:
//  blocks 0..127  : conv_w fp32 -> wbb bf16 in MFMA-fragment order:
//                   wbb[(((t*8 + i)*2 + ks)*64 + lane)*8 + j] =
//                     W[t*16 + (lane&15)][i*64 + ks*32 + (lane>>4)*8 + j]
//  blocks 128..131: cw fp32 -> cwb bf16 [k][c]
//  block  132     : c2[k] = ||cw_k||^2 ; zero asum
__global__ __launch_bounds__(256) void prep_kernel(
    const float* __restrict__ conv_w, const float* __restrict__ cw,
    __bf16* __restrict__ wbb, __bf16* __restrict__ cwb,
    float* __restrict__ c2, float* __restrict__ asum) {
    const int tid = threadIdx.x, bx = blockIdx.x;
    if (bx < 128) {
        const int idx  = bx * 256 + tid;          // [0, 32768)
        const int lane = idx & 63;
        const int ks   = (idx >> 6) & 1;
        const int ii   = (idx >> 7) & 7;
        const int t    = idx >> 10;
        const float* s = conv_w + (size_t)(t * 16 + (lane & 15)) * C
                         + ii * 64 + ks * 32 + (lane >> 4) * 8;
        bf16x8 o;
        #pragma unroll
        for (int j = 0; j < 8; j++) o[j] = (__bf16)s[j];
        *(bf16x8*)&wbb[(size_t)idx * 8] = o;
    } else if (bx < 132) {
        const int idx = ((bx - 128) * 256 + tid) * 16;   // [0, 16384) elems
        const float* s = cw + idx;
        __bf16* d = cwb + idx;
        bf16x8 o0, o1;
        #pragma unroll
        for (int j = 0; j < 8; j++) o0[j] = (__bf16)s[j];
        #pragma unroll
        for (int j = 0; j < 8; j++) o1[j] = (__bf16)s[8 + j];
        *(bf16x8*)&d[0] = o0;
        *(bf16x8*)&d[8] = o1;
    } else {
        if (tid < 32) {
            const float* r = cw + tid * 512;
            float s = 0.f;
            for (int c = 0; c < 512; c++) s += r[c] * r[c];
            c2[tid] = s;
        }
        if (tid < 128) asum[tid] = 0.f;
    }
}

// ---------------------------------------------------------------------------
// xpose: x fp32 [b][c][hw] -> xt bf16 [b][chunk=c/64][n][64 c-elems], with
// each 128-B output row's 16-B groups XOR-swizzled by (n&7) so conv's LDS
// (staged linearly via global_load_lds) is bank-conflict-free on frag reads.
// Tile: 64 c x 256 n. x read as 1-KB-per-row requests (4x conv-v1's 256 B).
// XR is source-swizzled (group ^= (r&7)^((r>>3)&7)) to kill the 8-way bank
// conflict of the column reads (lanes sharing n across 8 c8-groups).
__global__ __launch_bounds__(512) void xpose_kernel(
    const float* __restrict__ x, __bf16* __restrict__ xt) {
    __shared__ float XR[64 * 256];   // 64 KB
    const int tid = threadIdx.x, lane = tid & 63, wv = tid >> 6;
    const int nt = blockIdx.x, chunk = blockIdx.y, b = blockIdx.z;
    #pragma unroll
    for (int p = 0; p < 8; p++) {
        int r = wv * 8 + p;
        int s = (r & 7) ^ ((r >> 3) & 7);
        const float* gp = x + ((size_t)(b * C + chunk * 64 + r)) * HW
                          + nt * 256 + ((lane ^ s) * 4);
        load_lds16(gp, (char*)XR + r * 1024);
    }
    __syncthreads();
    const int c8 = tid & 7;
    #pragma unroll
    for (int k = 0; k < 4; k++) {
        int nloc = (tid >> 3) + k * 64;
        bf16x8 o;
        #pragma unroll
        for (int j = 0; j < 8; j++) {
            int cl = c8 * 8 + j;
            int g  = (nloc >> 2) ^ (j ^ c8);   // undo XR source swizzle
            o[j] = (__bf16)XR[cl * 256 + g * 4 + (nloc & 3)];
        }
        size_t rowbase = ((size_t)(b * 8 + chunk) * 16384 + nt * 256 + nloc) * 64;
        *(bf16x8*)&xt[rowbase + ((c8 ^ (nloc & 7)) * 8)] = o;
    }
}

// ---------------------------------------------------------------------------
// conv v3: plain GEMM on pre-transposed bf16 xt. No in-loop transpose.
// Stage = 8 KB fully-contiguous slab per chunk (8 x 1-KB sequential
// global_load_lds). LDS 16.6 KB; launch_bounds(256,3) -> VGPR<=170,
// 3 blocks/CU. One barrier per chunk; prefetch survives a full MFMA phase.
__global__ __launch_bounds__(256, 3) void conv_fused_v3_kernel(
    const __bf16* __restrict__ xt, const __bf16* __restrict__ wbb,
    const float* __restrict__ g2, const float* __restrict__ b2,
    const float* __restrict__ m2, const float* __restrict__ v2,
    __bf16* __restrict__ z, float* __restrict__ x2g) {
    __shared__ __bf16 XA[2][64 * 64];   // 2 x 8 KB
    __shared__ float  x2L[64];
    const int tid = threadIdx.x, lane = tid & 63, w = tid >> 6;
    const int l15 = lane & 15, q = lane >> 4;
    const int n0 = blockIdx.x * 64, b = blockIdx.y;
    if (tid < 64) x2L[tid] = 0.f;

    auto stage = [&](int chunk, int buf) {
        #pragma unroll
        for (int p = 0; p < 2; p++) {
            int seg = w * 2 + p;                 // 8 segs of 1 KB, sequential
            const __bf16* gp = xt + ((size_t)(b * 8 + chunk) * 16384 + n0 + seg * 8) * 64
                               + lane * 8;
            load_lds16(gp, (char*)XA[buf] + seg * 1024);
        }
    };

    floatx4 acc[4][8];
    const floatx4 zv4 = {0.f, 0.f, 0.f, 0.f};
    #pragma unroll
    for (int mt = 0; mt < 4; mt++)
        #pragma unroll
        for (int ot = 0; ot < 8; ot++) acc[mt][ot] = zv4;

    stage(0, 0);
    for (int i = 0; i < 8; i++) {
        const int buf = i & 1;
        __syncthreads();                    // chunk i landed; prev MFMA done
        if (i < 7) stage(i + 1, buf ^ 1);   // in flight across the MFMA phase
        #pragma unroll
        for (int ks = 0; ks < 2; ks++) {
            bf16x8 af[4];
            #pragma unroll
            for (int mt = 0; mt < 4; mt++) {
                int row = mt * 16 + l15;
                af[mt] = *(const bf16x8*)((const char*)XA[buf]
                          + row * 128 + (((ks * 4 + q) ^ (row & 7)) * 16));
            }
            #pragma unroll
            for (int og = 0; og < 2; og++) {
                bf16x8 bfv[4];
                #pragma unroll
                for (int o4 = 0; o4 < 4; o4++) {
                    int ot = og * 4 + o4;
                    bfv[o4] = *(const bf16x8*)&wbb[
                        ((size_t)(((w * 8 + ot) * 8 + i) * 2 + ks) * 64 + lane) * 8];
                }
                #pragma unroll
                for (int mt = 0; mt < 4; mt++)
                    #pragma unroll
                    for (int o4 = 0; o4 < 4; o4++)
                        acc[mt][og * 4 + o4] = __builtin_amdgcn_mfma_f32_16x16x32_bf16(
                            af[mt], bfv[o4], acc[mt][og * 4 + o4], 0, 0, 0);
            }
        }
    }
    // epilogue: BN + ReLU + store z bf16 + x2 partials
    float s8[8], bi8[8];
    #pragma unroll
    for (int ot = 0; ot < 8; ot++) {
        int o = w * 128 + ot * 16 + l15;
        float s = g2[o] * rsqrtf(v2[o] + EPS);
        s8[ot] = s; bi8[ot] = b2[o] - m2[o] * s;
    }
    float xx[16];
    #pragma unroll
    for (int t = 0; t < 16; t++) xx[t] = 0.f;
    #pragma unroll
    for (int mt = 0; mt < 4; mt++)
        #pragma unroll
        for (int reg = 0; reg < 4; reg++) {
            int n = n0 + mt * 16 + q * 4 + reg;
            #pragma unroll
            for (int ot = 0; ot < 8; ot++) {
                float v = fmaxf(acc[mt][ot][reg] * s8[ot] + bi8[ot], 0.f);
                z[((size_t)(b * HW + n)) * C + w * 128 + ot * 16 + l15] = (__bf16)v;
                xx[mt * 4 + reg] += v * v;
            }
        }
    #pragma unroll
    for (int t = 0; t < 16; t++) {
        float v = xx[t];
        v += __shfl_xor(v, 1); v += __shfl_xor(v, 2);
        v += __shfl_xor(v, 4); v += __shfl_xor(v, 8);
        xx[t] = v;
    }
    if (l15 == 0) {
        #pragma unroll
        for (int mt = 0; mt < 4; mt++)
            #pragma unroll
            for (int reg = 0; reg < 4; reg++)
                atomicAdd(&x2L[mt * 16 + q * 4 + reg], xx[mt * 4 + reg]);
    }
    __syncthreads();
    if (tid < 64) x2g[(size_t)b * HW + n0 + tid] = x2L[tid];
}

// ---------------------------------------------------------------------------
// fallback conv (R1 version) — used when ws_size can't hold xt.
__global__ __launch_bounds__(256) void conv_fused_fb_kernel(
    const float* __restrict__ x, const __bf16* __restrict__ wbb,
    const float* __restrict__ g2, const float* __restrict__ b2,
    const float* __restrict__ m2, const float* __restrict__ v2,
    __bf16* __restrict__ z, float* __restrict__ x2g) {
    __shared__ float  XR[2][64 * 64];
    __shared__ __bf16 XA[64 * 72];
    __shared__ float  x2L[64];
    const int tid = threadIdx.x, lane = tid & 63, w = tid >> 6;
    const int l15 = lane & 15, q = lane >> 4;
    const int n0 = blockIdx.x * 64, b = blockIdx.y;
    if (tid < 64) x2L[tid] = 0.f;

    auto stage = [&](int chunk, int buf) {
        #pragma unroll
        for (int p = 0; p < 4; p++) {
            int seg = w * 4 + p;
            int cr = chunk * 64 + seg * 4 + (lane >> 4);
            const float* gp = x + ((size_t)(b * C + cr)) * HW + n0 + (lane & 15) * 4;
            load_lds16(gp, (char*)XR[buf] + seg * 1024);
        }
    };

    floatx4 acc[4][8];
    const floatx4 zv4 = {0.f, 0.f, 0.f, 0.f};
    #pragma unroll
    for (int mt = 0; mt < 4; mt++)
        #pragma unroll
        for (int ot = 0; ot < 8; ot++) acc[mt][ot] = zv4;

    stage(0, 0);
    for (int i = 0; i < 8; i++) {
        const int cur = i & 1;
        __syncthreads();
        if (i < 7) stage(i + 1, cur ^ 1);
        #pragma unroll
        for (int f = 0; f < 2; f++) {
            int id = f * 256 + tid;
            int n = id & 63, cs = id >> 6;
            bf16x8 o;
            #pragma unroll
            for (int j = 0; j < 8; j++) o[j] = (__bf16)XR[cur][(cs * 8 + j) * 64 + n];
            *(bf16x8*)&XA[n * 72 + cs * 8] = o;
        }
        asm volatile("s_waitcnt lgkmcnt(0)" ::: "memory");
        __builtin_amdgcn_sched_barrier(0);
        __builtin_amdgcn_s_barrier();
        __builtin_amdgcn_sched_barrier(0);
        #pragma unroll
        for (int ks = 0; ks < 2; ks++) {
            bf16x8 af[4], bfv[8];
            #pragma unroll
            for (int ot = 0; ot < 8; ot++)
                bfv[ot] = *(const bf16x8*)&wbb[
                    ((size_t)(((w * 8 + ot) * 8 + i) * 2 + ks) * 64 + lane) * 8];
            #pragma unroll
            for (int mt = 0; mt < 4; mt++)
                af[mt] = *(const bf16x8*)&XA[(mt * 16 + l15) * 72 + ks * 32 + q * 8];
            #pragma unroll
            for (int mt = 0; mt < 4; mt++)
                #pragma unroll
                for (int ot = 0; ot < 8; ot++)
                    acc[mt][ot] = __builtin_amdgcn_mfma_f32_16x16x32_bf16(
                        af[mt], bfv[ot], acc[mt][ot], 0, 0, 0);
        }
    }
    float s8[8], bi8[8];
    #pragma unroll
    for (int ot = 0; ot < 8; ot++) {
        int o = w * 128 + ot * 16 + l15;
        float s = g2[o] * rsqrtf(v2[o] + EPS);
        s8[ot] = s; bi8[ot] = b2[o] - m2[o] * s;
    }
    float xx[16];
    #pragma unroll
    for (int t = 0; t < 16; t++) xx[t] = 0.f;
    #pragma unroll
    for (int mt = 0; mt < 4; mt++)
        #pragma unroll
        for (int reg = 0; reg < 4; reg++) {
            int n = n0 + mt * 16 + q * 4 + reg;
            #pragma unroll
            for (int ot = 0; ot < 8; ot++) {
                float v = fmaxf(acc[mt][ot][reg] * s8[ot] + bi8[ot], 0.f);
                z[((size_t)(b * HW + n)) * C + w * 128 + ot * 16 + l15] = (__bf16)v;
                xx[mt * 4 + reg] += v * v;
            }
        }
    #pragma unroll
    for (int t = 0; t < 16; t++) {
        float v = xx[t];
        v += __shfl_xor(v, 1); v += __shfl_xor(v, 2);
        v += __shfl_xor(v, 4); v += __shfl_xor(v, 8);
        xx[t] = v;
    }
    if (l15 == 0) {
        #pragma unroll
        for (int mt = 0; mt < 4; mt++)
            #pragma unroll
            for (int reg = 0; reg < 4; reg++)
                atomicAdd(&x2L[mt * 16 + q * 4 + reg], xx[mt * 4 + reg]);
    }
    __syncthreads();
    if (tid < 64) x2g[(size_t)b * HW + n0 + tid] = x2L[tid];
}

// ---------------------------------------------------------------------------
// fused assign+agg (unchanged)
__global__ __launch_bounds__(256) void assign_agg_kernel(
    const __bf16* __restrict__ zb, const __bf16* __restrict__ cwb,
    const float* __restrict__ scale, const float* __restrict__ c2,
    const float* __restrict__ x2g, float* __restrict__ part,
    float* __restrict__ asum) {
    __shared__ __bf16 ZT[32][528];
    __shared__ float  LG[32][33];
    __shared__ __bf16 AT[32][40];
    __shared__ float  asum_l[32];
    const int tid = threadIdx.x, lane = tid & 63, w = tid >> 6;
    const int l15 = lane & 15, q = lane >> 4;
    const int b = blockIdx.y, bx = blockIdx.x;
    if (tid < 32) asum_l[tid] = 0.f;
    float sck[8], c2k[8];
    #pragma unroll
    for (int j = 0; j < 8; j++) { sck[j] = scale[q * 8 + j]; c2k[j] = c2[q * 8 + j]; }
    const int mt_ = w >> 1, nt_ = w & 1;

    floatx4 agga[2][8];
    const floatx4 zv4 = {0.f, 0.f, 0.f, 0.f};
    #pragma unroll
    for (int mt = 0; mt < 2; mt++)
        #pragma unroll
        for (int ct = 0; ct < 8; ct++) agga[mt][ct] = zv4;

    for (int s = 0; s < 4; s++) {
        const int nb = bx * 128 + s * 32;
        bf16x8 st[8];
        #pragma unroll
        for (int p = 0; p < 8; p++) {
            int e = (p * 256 + tid) * 8;
            int n = e >> 9, c = e & 511;
            st[p] = *(const bf16x8*)&zb[((size_t)(b * HW + nb + n)) * C + c];
        }
        __syncthreads();
        #pragma unroll
        for (int p = 0; p < 8; p++) {
            int e = (p * 256 + tid) * 8;
            int n = e >> 9, c = e & 511;
            *(bf16x8*)&ZT[n][c] = st[p];
        }
        __syncthreads();
        floatx4 la = zv4;
        #pragma unroll
        for (int kc = 0; kc < 16; kc++) {
            bf16x8 a  = *(const bf16x8*)&cwb[(size_t)(mt_ * 16 + l15) * C + kc * 32 + q * 8];
            bf16x8 bb = *(const bf16x8*)&ZT[nt_ * 16 + l15][kc * 32 + q * 8];
            la = __builtin_amdgcn_mfma_f32_16x16x32_bf16(a, bb, la, 0, 0, 0);
        }
        #pragma unroll
        for (int r = 0; r < 4; r++)
            LG[mt_ * 16 + q * 4 + r][nt_ * 16 + l15] = la[r];
        __syncthreads();
        if (w < 2) {
            int nl = w * 16 + l15;
            float x2v = x2g[(size_t)b * HW + nb + nl];
            float lg[8];
            float mx = -1e30f;
            #pragma unroll
            for (int j = 0; j < 8; j++) {
                float t = sck[j] * (x2v - 2.f * LG[q * 8 + j][nl] + c2k[j]);
                lg[j] = t; mx = fmaxf(mx, t);
            }
            mx = fmaxf(mx, __shfl_xor(mx, 16));
            mx = fmaxf(mx, __shfl_xor(mx, 32));
            float se = 0.f;
            #pragma unroll
            for (int j = 0; j < 8; j++) { lg[j] = __expf(lg[j] - mx); se += lg[j]; }
            se += __shfl_xor(se, 16);
            se += __shfl_xor(se, 32);
            float inv = 1.f / se;
            #pragma unroll
            for (int j = 0; j < 8; j++) {
                float a = lg[j] * inv;
                AT[q * 8 + j][nl] = (__bf16)a;
                lg[j] = a;
            }
            #pragma unroll
            for (int j = 0; j < 8; j++) {
                float v = lg[j];
                v += __shfl_xor(v, 1); v += __shfl_xor(v, 2);
                v += __shfl_xor(v, 4); v += __shfl_xor(v, 8);
                if (l15 == 0) atomicAdd(&asum_l[q * 8 + j], v);
            }
        }
        __syncthreads();
        bf16x8 afr0 = *(const bf16x8*)&AT[l15][q * 8];
        bf16x8 afr1 = *(const bf16x8*)&AT[16 + l15][q * 8];
        #pragma unroll
        for (int ct = 0; ct < 8; ct++) {
            int c = w * 128 + ct * 16 + l15;
            bf16x8 bb;
            #pragma unroll
            for (int j = 0; j < 8; j++) bb[j] = ZT[q * 8 + j][c];
            agga[0][ct] = __builtin_amdgcn_mfma_f32_16x16x32_bf16(afr0, bb, agga[0][ct], 0, 0, 0);
            agga[1][ct] = __builtin_amdgcn_mfma_f32_16x16x32_bf16(afr1, bb, agga[1][ct], 0, 0, 0);
        }
    }
    float* pp = part + ((size_t)(b * 128 + bx) * K) * C;
    #pragma unroll
    for (int mt = 0; mt < 2; mt++)
        #pragma unroll
        for (int ct = 0; ct < 8; ct++)
            #pragma unroll
            for (int r = 0; r < 4; r++)
                pp[(size_t)(mt * 16 + q * 4 + r) * C + w * 128 + ct * 16 + l15] =
                    agga[mt][ct][r];
    __syncthreads();
    if (tid < 32) atomicAdd(&asum[b * K + tid], asum_l[tid]);
}

// ---------------------------------------------------------------------------
__global__ __launch_bounds__(512) void agg_reduce_kernel(
    const float* __restrict__ part, float* __restrict__ agg) {
    const int k = blockIdx.x, b = blockIdx.y, c = threadIdx.x;
    float s = 0.f;
    for (int p = 0; p < 128; p++)
        s += part[((size_t)((b * 128 + p) * K + k)) * C + c];
    agg[((size_t)(b * K + k)) * C + c] = s;
}

// ---------------------------------------------------------------------------
__global__ __launch_bounds__(512) void feat_kernel(
    const float* __restrict__ cw,
    const float* __restrict__ g1, const float* __restrict__ b1,
    const float* __restrict__ m1, const float* __restrict__ v1,
    const float* __restrict__ fcw, const float* __restrict__ fcb,
    const float* __restrict__ agg, const float* __restrict__ asum,
    float* __restrict__ gamma, float* __restrict__ out_feat) {
    __shared__ float featL[C];
    const int tid = threadIdx.x;
    const int b = blockIdx.x;
    float f = 0.f;
    for (int kk = 0; kk < K; kk++) {
        float s = g1[kk] * rsqrtf(v1[kk] + EPS);
        float bias = b1[kk] - m1[kk] * s;
        float e = agg[((size_t)b * K + kk) * C + tid] - asum[b * K + kk] * cw[kk * C + tid];
        f += fmaxf(e * s + bias, 0.f);
    }
    f *= (1.f / 32.f);
    out_feat[b * C + tid] = f;
    featL[tid] = f;
    __syncthreads();
    const int w = tid >> 6, l = tid & 63;
    for (int cc = w * 64; cc < w * 64 + 64; cc++) {
        const float* row = &fcw[(size_t)cc * C + l * 8];
        float4 fa = *(const float4*)&featL[l * 8];
        float4 fb = *(const float4*)&featL[l * 8 + 4];
        float4 wa = *(const float4*)row;
        float4 wb = *(const float4*)(row + 4);
        float s = fa.x * wa.x + fa.y * wa.y + fa.z * wa.z + fa.w * wa.w
                + fb.x * wb.x + fb.y * wb.y + fb.z * wb.z + fb.w * wb.w;
        #pragma unroll
        for (int d = 32; d >= 1; d >>= 1) s += __shfl_xor(s, d);
        if (l == 0) gamma[b * C + cc] = 1.f / (1.f + __expf(-(s + fcb[cc])));
    }
}

// ---------------------------------------------------------------------------
__global__ __launch_bounds__(256) void gate_kernel(const float* __restrict__ x,
                                                   const float* __restrict__ gamma,
                                                   float* __restrict__ out) {
    size_t idx = (size_t)blockIdx.x * 256 + threadIdx.x;
    int bc = (int)(idx >> 12);
    float gm = 1.f + gamma[bc];
    float4 xv = ((const float4*)x)[idx];
    float4 r;
    r.x = fmaxf(xv.x * gm, 0.f);
    r.y = fmaxf(xv.y * gm, 0.f);
    r.z = fmaxf(xv.z * gm, 0.f);
    r.w = fmaxf(xv.w * gm, 0.f);
    ((float4*)out)[idx] = r;
}

// ---------------------------------------------------------------------------
extern "C" void kernel_launch(void* const* d_in, const int* in_sizes, int n_in,
                              void* d_out, int out_size, void* d_ws, size_t ws_size,
                              hipStream_t stream) {
    const float* x      = (const float*)d_in[0];
    const float* conv_w = (const float*)d_in[1];
    const float* bn2_g  = (const float*)d_in[2];
    const float* bn2_b  = (const float*)d_in[3];
    const float* bn2_m  = (const float*)d_in[4];
    const float* bn2_v  = (const float*)d_in[5];
    const float* cw     = (const float*)d_in[6];
    const float* scale  = (const float*)d_in[7];
    const float* bn1_g  = (const float*)d_in[8];
    const float* bn1_b  = (const float*)d_in[9];
    const float* bn1_m  = (const float*)d_in[10];
    const float* bn1_v  = (const float*)d_in[11];
    const float* fcw    = (const float*)d_in[12];
    const float* fcb    = (const float*)d_in[13];
    char* wsb = (char*)d_ws;
    __bf16* zbuf  = (__bf16*)(wsb + Z_OFF);
    __bf16* wbb   = (__bf16*)(wsb + WBB_OFF);
    __bf16* cwb   = (__bf16*)(wsb + CWB_OFF);
    float*  x2    = (float*)(wsb + X2_OFF);
    float*  c2    = (float*)(wsb + C2_OFF);
    float*  asum  = (float*)(wsb + ASUM_OFF);
    float*  part  = (float*)(wsb + PART_OFF);
    float*  agg   = (float*)(wsb + AGG_OFF);
    float*  gamma = (float*)(wsb + GAMMA_OFF);
    __bf16* xt    = (__bf16*)(wsb + XT_OFF);
    float* out = (float*)d_out;

    prep_kernel<<<133, 256, 0, stream>>>(conv_w, cw, wbb, cwb, c2, asum);
    if (ws_size >= WS_NEEDED) {
        xpose_kernel<<<dim3(64, 8, 4), 512, 0, stream>>>(x, xt);
        conv_fused_v3_kernel<<<dim3(256, 4), 256, 0, stream>>>(
            xt, wbb, bn2_g, bn2_b, bn2_m, bn2_v, zbuf, x2);
    } else {
        conv_fused_fb_kernel<<<dim3(256, 4), 256, 0, stream>>>(
            x, wbb, bn2_g, bn2_b, bn2_m, bn2_v, zbuf, x2);
    }
    assign_agg_kernel<<<dim3(128, 4), 256, 0, stream>>>(
        zbuf, cwb, scale, c2, x2, part, asum);
    agg_reduce_kernel<<<dim3(32, 4), 512, 0, stream>>>(part, agg);
    feat_kernel<<<4, 512, 0, stream>>>(cw, bn1_g, bn1_b, bn1_m, bn1_v,
                                       fcw, fcb, agg, asum, gamma, out);
    gate_kernel<<<32768, 256, 0, stream>>>(x, gamma, out + B * C);
}

// Round 4
// 459.162 us; speedup vs baseline: 1.4299x; 1.4299x over previous
//
#include <hip/hip_runtime.h>
#include <cstdint>

#define EPS 1e-5f
constexpr int B = 4, C = 512, HW = 16384, K = 32;

typedef __bf16 bf16x8 __attribute__((ext_vector_type(8)));
typedef float  floatx4 __attribute__((ext_vector_type(4)));
typedef unsigned int u32;

__device__ __forceinline__ void load_lds16(const void* g, void* l) {
    __builtin_amdgcn_global_load_lds((const __attribute__((address_space(1))) u32*)g,
                                     (__attribute__((address_space(3))) u32*)l,
                                     16, 0, 0);
}

// ---------------------------------------------------------------------------
// workspace byte offsets
constexpr size_t Z_OFF     = 0;            // z bf16 [b][n][c]    67,108,864
constexpr size_t WBB_OFF   = 67108864;     // W bf16 frag-swizzled   524,288
constexpr size_t CWB_OFF   = 67633152;     // cw bf16 [k][c]          32,768
constexpr size_t X2_OFF    = 67665920;     // fp32 [b*HW]            262,144
constexpr size_t C2_OFF    = 67928064;     // fp32 [K]
constexpr size_t ASUM_OFF  = 67928192;     // fp32 [B*K]
constexpr size_t PART_OFF  = 67928704;     // fp32 [B][128][K][C] 33,554,432
constexpr size_t AGG_OFF   = 101483136;    // fp32 [B][K][C]         262,144
constexpr size_t GAMMA_OFF = 101745280;    // fp32 [B][C]              8,192

// ---------------------------------------------------------------------------
// prep:
//  blocks 0..127  : conv_w fp32 -> wbb bf16 in MFMA-fragment order:
//                   wbb[(((t*8 + i)*2 + ks)*64 + lane)*8 + j] =
//                     W[t*16 + (lane&15)][i*64 + ks*32 + (lane>>4)*8 + j]
//  blocks 128..131: cw fp32 -> cwb bf16 [k][c]
//  block  132     : c2[k] = ||cw_k||^2 ; zero asum
__global__ __launch_bounds__(256) void prep_kernel(
    const float* __restrict__ conv_w, const float* __restrict__ cw,
    __bf16* __restrict__ wbb, __bf16* __restrict__ cwb,
    float* __restrict__ c2, float* __restrict__ asum) {
    const int tid = threadIdx.x, bx = blockIdx.x;
    if (bx < 128) {
        const int idx  = bx * 256 + tid;          // [0, 32768)
        const int lane = idx & 63;
        const int ks   = (idx >> 6) & 1;
        const int ii   = (idx >> 7) & 7;
        const int t    = idx >> 10;
        const float* s = conv_w + (size_t)(t * 16 + (lane & 15)) * C
                         + ii * 64 + ks * 32 + (lane >> 4) * 8;
        bf16x8 o;
        #pragma unroll
        for (int j = 0; j < 8; j++) o[j] = (__bf16)s[j];
        *(bf16x8*)&wbb[(size_t)idx * 8] = o;
    } else if (bx < 132) {
        const int idx = ((bx - 128) * 256 + tid) * 16;   // [0, 16384) elems
        const float* s = cw + idx;
        __bf16* d = cwb + idx;
        bf16x8 o0, o1;
        #pragma unroll
        for (int j = 0; j < 8; j++) o0[j] = (__bf16)s[j];
        #pragma unroll
        for (int j = 0; j < 8; j++) o1[j] = (__bf16)s[8 + j];
        *(bf16x8*)&d[0] = o0;
        *(bf16x8*)&d[8] = o1;
    } else {
        if (tid < 32) {
            const float* r = cw + tid * 512;
            float s = 0.f;
            for (int c = 0; c < 512; c++) s += r[c] * r[c];
            c2[tid] = s;
        }
        if (tid < 128) asum[tid] = 0.f;
    }
}

// ---------------------------------------------------------------------------
// fused conv (R1-measured version, 116 us): transpose x in LDS + GEMM + BN +
// ReLU + x2. Raw-barrier pipeline: prefetch chunk i+1 survives the MFMA phase.
__global__ __launch_bounds__(256) void conv_fused_kernel(
    const float* __restrict__ x, const __bf16* __restrict__ wbb,
    const float* __restrict__ g2, const float* __restrict__ b2,
    const float* __restrict__ m2, const float* __restrict__ v2,
    __bf16* __restrict__ z, float* __restrict__ x2g) {
    __shared__ float  XR[2][64 * 64];   // [chunk c][n] fp32, 2x16 KB
    __shared__ __bf16 XA[64 * 72];      // [n][c-in-chunk], 9 KB
    __shared__ float  x2L[64];
    const int tid = threadIdx.x, lane = tid & 63, w = tid >> 6;
    const int l15 = lane & 15, q = lane >> 4;
    const int n0 = blockIdx.x * 64, b = blockIdx.y;
    if (tid < 64) x2L[tid] = 0.f;

    auto stage = [&](int chunk, int buf) {
        #pragma unroll
        for (int p = 0; p < 4; p++) {
            int seg = w * 4 + p;                    // 16 segs of 4 c-rows
            int cr = chunk * 64 + seg * 4 + (lane >> 4);
            const float* gp = x + ((size_t)(b * C + cr)) * HW + n0 + (lane & 15) * 4;
            load_lds16(gp, (char*)XR[buf] + seg * 1024);
        }
    };

    floatx4 acc[4][8];
    const floatx4 zv4 = {0.f, 0.f, 0.f, 0.f};
    #pragma unroll
    for (int mt = 0; mt < 4; mt++)
        #pragma unroll
        for (int ot = 0; ot < 8; ot++) acc[mt][ot] = zv4;

    stage(0, 0);
    for (int i = 0; i < 8; i++) {
        const int cur = i & 1;
        __syncthreads();                    // chunk i landed; XA free
        if (i < 7) stage(i + 1, cur ^ 1);   // prefetch survives raw barrier
        #pragma unroll
        for (int f = 0; f < 2; f++) {
            int id = f * 256 + tid;
            int n = id & 63, cs = id >> 6;
            bf16x8 o;
            #pragma unroll
            for (int j = 0; j < 8; j++) o[j] = (__bf16)XR[cur][(cs * 8 + j) * 64 + n];
            *(bf16x8*)&XA[n * 72 + cs * 8] = o;
        }
        asm volatile("s_waitcnt lgkmcnt(0)" ::: "memory");
        __builtin_amdgcn_sched_barrier(0);
        __builtin_amdgcn_s_barrier();       // XA ready; prefetch NOT drained
        __builtin_amdgcn_sched_barrier(0);
        #pragma unroll
        for (int ks = 0; ks < 2; ks++) {
            bf16x8 af[4], bfv[8];
            #pragma unroll
            for (int ot = 0; ot < 8; ot++)
                bfv[ot] = *(const bf16x8*)&wbb[
                    ((size_t)(((w * 8 + ot) * 8 + i) * 2 + ks) * 64 + lane) * 8];
            #pragma unroll
            for (int mt = 0; mt < 4; mt++)
                af[mt] = *(const bf16x8*)&XA[(mt * 16 + l15) * 72 + ks * 32 + q * 8];
            #pragma unroll
            for (int mt = 0; mt < 4; mt++)
                #pragma unroll
                for (int ot = 0; ot < 8; ot++)
                    acc[mt][ot] = __builtin_amdgcn_mfma_f32_16x16x32_bf16(
                        af[mt], bfv[ot], acc[mt][ot], 0, 0, 0);
        }
    }
    // epilogue: BN + ReLU + store z bf16 + x2 partials
    float s8[8], bi8[8];
    #pragma unroll
    for (int ot = 0; ot < 8; ot++) {
        int o = w * 128 + ot * 16 + l15;
        float s = g2[o] * rsqrtf(v2[o] + EPS);
        s8[ot] = s; bi8[ot] = b2[o] - m2[o] * s;
    }
    float xx[16];
    #pragma unroll
    for (int t = 0; t < 16; t++) xx[t] = 0.f;
    #pragma unroll
    for (int mt = 0; mt < 4; mt++)
        #pragma unroll
        for (int reg = 0; reg < 4; reg++) {
            int n = n0 + mt * 16 + q * 4 + reg;
            #pragma unroll
            for (int ot = 0; ot < 8; ot++) {
                float v = fmaxf(acc[mt][ot][reg] * s8[ot] + bi8[ot], 0.f);
                z[((size_t)(b * HW + n)) * C + w * 128 + ot * 16 + l15] = (__bf16)v;
                xx[mt * 4 + reg] += v * v;
            }
        }
    #pragma unroll
    for (int t = 0; t < 16; t++) {
        float v = xx[t];
        v += __shfl_xor(v, 1); v += __shfl_xor(v, 2);
        v += __shfl_xor(v, 4); v += __shfl_xor(v, 8);
        xx[t] = v;
    }
    if (l15 == 0) {
        #pragma unroll
        for (int mt = 0; mt < 4; mt++)
            #pragma unroll
            for (int reg = 0; reg < 4; reg++)
                atomicAdd(&x2L[mt * 16 + q * 4 + reg], xx[mt * 4 + reg]);
    }
    __syncthreads();
    if (tid < 64) x2g[(size_t)b * HW + n0 + tid] = x2L[tid];
}

// ---------------------------------------------------------------------------
// fused assign+agg v2: software-pipelined.
// Per 32-n subtile: ZT write from regs -> prefetch next subtile (survives raw
// barriers) -> assign MFMA -> softmax (hoisted x2) -> agg MFMA.
// Only the loop-top __syncthreads drains vmcnt (loads landed by then).
__global__ __launch_bounds__(256) void assign_agg_kernel(
    const __bf16* __restrict__ zb, const __bf16* __restrict__ cwb,
    const float* __restrict__ scale, const float* __restrict__ c2,
    const float* __restrict__ x2g, float* __restrict__ part,
    float* __restrict__ asum) {
    __shared__ __bf16 ZT[32][536];   // 33.5 KB; stride 268 words -> 2-way banks
    __shared__ float  LG[32][33];    // logits [k][n]
    __shared__ __bf16 AT[32][40];    // assign [k][n]
    __shared__ float  asum_l[32];
    const int tid = threadIdx.x, lane = tid & 63, w = tid >> 6;
    const int l15 = lane & 15, q = lane >> 4;
    const int b = blockIdx.y, bx = blockIdx.x;
    if (tid < 32) asum_l[tid] = 0.f;
    float sck[8], c2k[8];
    #pragma unroll
    for (int j = 0; j < 8; j++) { sck[j] = scale[q * 8 + j]; c2k[j] = c2[q * 8 + j]; }
    const int mt_ = w >> 1, nt_ = w & 1;

    // hoisted x2 loads (only waves 0,1 consume them in softmax)
    float x2r[4];
    if (w < 2) {
        #pragma unroll
        for (int s = 0; s < 4; s++)
            x2r[s] = x2g[(size_t)b * HW + bx * 128 + s * 32 + w * 16 + l15];
    }

    floatx4 agga[2][8];
    const floatx4 zv4 = {0.f, 0.f, 0.f, 0.f};
    #pragma unroll
    for (int mt = 0; mt < 2; mt++)
        #pragma unroll
        for (int ct = 0; ct < 8; ct++) agga[mt][ct] = zv4;

    // prologue: load subtile 0 into regs
    bf16x8 st[8];
    #pragma unroll
    for (int p = 0; p < 8; p++) {
        int e = (p * 256 + tid) * 8;
        st[p] = *(const bf16x8*)&zb[((size_t)(b * HW + bx * 128 + (e >> 9))) * C + (e & 511)];
    }

    for (int s = 0; s < 4; s++) {
        const int nb = bx * 128 + s * 32;
        __syncthreads();   // prev agg done reading ZT; drains vm (st landed)
        #pragma unroll
        for (int p = 0; p < 8; p++) {
            int e = (p * 256 + tid) * 8;
            *(bf16x8*)&ZT[e >> 9][e & 511] = st[p];
        }
        if (s < 3) {       // prefetch next subtile; in flight across raw barriers
            #pragma unroll
            for (int p = 0; p < 8; p++) {
                int e = (p * 256 + tid) * 8;
                st[p] = *(const bf16x8*)&zb[
                    ((size_t)(b * HW + nb + 32 + (e >> 9))) * C + (e & 511)];
            }
        }
        asm volatile("s_waitcnt lgkmcnt(0)" ::: "memory");
        __builtin_amdgcn_sched_barrier(0);
        __builtin_amdgcn_s_barrier();       // ZT ready
        __builtin_amdgcn_sched_barrier(0);
        // ---- assign MFMA: each wave one (mt_, nt_) 16x16 tile, full K=512
        floatx4 la = zv4;
        #pragma unroll
        for (int kc = 0; kc < 16; kc++) {
            bf16x8 a  = *(const bf16x8*)&cwb[(size_t)(mt_ * 16 + l15) * C + kc * 32 + q * 8];
            bf16x8 bb = *(const bf16x8*)&ZT[nt_ * 16 + l15][kc * 32 + q * 8];
            la = __builtin_amdgcn_mfma_f32_16x16x32_bf16(a, bb, la, 0, 0, 0);
        }
        #pragma unroll
        for (int r = 0; r < 4; r++)
            LG[mt_ * 16 + q * 4 + r][nt_ * 16 + l15] = la[r];
        asm volatile("s_waitcnt lgkmcnt(0)" ::: "memory");
        __builtin_amdgcn_sched_barrier(0);
        __builtin_amdgcn_s_barrier();       // LG ready
        __builtin_amdgcn_sched_barrier(0);
        // ---- softmax over k (waves 0,1 cover the 32 n-columns)
        if (w < 2) {
            int nl = w * 16 + l15;
            float lg[8];
            float mx = -1e30f;
            #pragma unroll
            for (int j = 0; j < 8; j++) {
                float t = sck[j] * (x2r[s] - 2.f * LG[q * 8 + j][nl] + c2k[j]);
                lg[j] = t; mx = fmaxf(mx, t);
            }
            mx = fmaxf(mx, __shfl_xor(mx, 16));
            mx = fmaxf(mx, __shfl_xor(mx, 32));
            float se = 0.f;
            #pragma unroll
            for (int j = 0; j < 8; j++) { lg[j] = __expf(lg[j] - mx); se += lg[j]; }
            se += __shfl_xor(se, 16);
            se += __shfl_xor(se, 32);
            float inv = 1.f / se;
            #pragma unroll
            for (int j = 0; j < 8; j++) {
                float a = lg[j] * inv;
                AT[q * 8 + j][nl] = (__bf16)a;
                lg[j] = a;
            }
            #pragma unroll
            for (int j = 0; j < 8; j++) {
                float v = lg[j];
                v += __shfl_xor(v, 1); v += __shfl_xor(v, 2);
                v += __shfl_xor(v, 4); v += __shfl_xor(v, 8);
                if (l15 == 0) atomicAdd(&asum_l[q * 8 + j], v);
            }
        }
        asm volatile("s_waitcnt lgkmcnt(0)" ::: "memory");
        __builtin_amdgcn_sched_barrier(0);
        __builtin_amdgcn_s_barrier();       // AT ready
        __builtin_amdgcn_sched_barrier(0);
        // ---- agg MFMA: Kdim = 32 n (one chunk); per wave 8 c-tiles
        bf16x8 afr0 = *(const bf16x8*)&AT[l15][q * 8];
        bf16x8 afr1 = *(const bf16x8*)&AT[16 + l15][q * 8];
        #pragma unroll
        for (int ct = 0; ct < 8; ct++) {
            int c = w * 128 + ct * 16 + l15;
            bf16x8 bb;
            #pragma unroll
            for (int j = 0; j < 8; j++) bb[j] = ZT[q * 8 + j][c];
            agga[0][ct] = __builtin_amdgcn_mfma_f32_16x16x32_bf16(afr0, bb, agga[0][ct], 0, 0, 0);
            agga[1][ct] = __builtin_amdgcn_mfma_f32_16x16x32_bf16(afr1, bb, agga[1][ct], 0, 0, 0);
        }
    }
    // epilogue: per-block agg partials
    float* pp = part + ((size_t)(b * 128 + bx) * K) * C;
    #pragma unroll
    for (int mt = 0; mt < 2; mt++)
        #pragma unroll
        for (int ct = 0; ct < 8; ct++)
            #pragma unroll
            for (int r = 0; r < 4; r++)
                pp[(size_t)(mt * 16 + q * 4 + r) * C + w * 128 + ct * 16 + l15] =
                    agga[mt][ct][r];
    __syncthreads();
    if (tid < 32) atomicAdd(&asum[b * K + tid], asum_l[tid]);
}

// ---------------------------------------------------------------------------
__global__ __launch_bounds__(512) void agg_reduce_kernel(
    const float* __restrict__ part, float* __restrict__ agg) {
    const int k = blockIdx.x, b = blockIdx.y, c = threadIdx.x;
    float s = 0.f;
    for (int p = 0; p < 128; p++)
        s += part[((size_t)((b * 128 + p) * K + k)) * C + c];
    agg[((size_t)(b * K + k)) * C + c] = s;
}

// ---------------------------------------------------------------------------
// feat = mean_k relu(bn1(agg - asum*cw)); gamma = sigmoid(fc_w @ feat + fc_b)
__global__ __launch_bounds__(512) void feat_kernel(
    const float* __restrict__ cw,
    const float* __restrict__ g1, const float* __restrict__ b1,
    const float* __restrict__ m1, const float* __restrict__ v1,
    const float* __restrict__ fcw, const float* __restrict__ fcb,
    const float* __restrict__ agg, const float* __restrict__ asum,
    float* __restrict__ gamma, float* __restrict__ out_feat) {
    __shared__ float featL[C];
    const int tid = threadIdx.x;
    const int b = blockIdx.x;
    float f = 0.f;
    for (int kk = 0; kk < K; kk++) {
        float s = g1[kk] * rsqrtf(v1[kk] + EPS);
        float bias = b1[kk] - m1[kk] * s;
        float e = agg[((size_t)b * K + kk) * C + tid] - asum[b * K + kk] * cw[kk * C + tid];
        f += fmaxf(e * s + bias, 0.f);
    }
    f *= (1.f / 32.f);
    out_feat[b * C + tid] = f;
    featL[tid] = f;
    __syncthreads();
    const int w = tid >> 6, l = tid & 63;
    for (int cc = w * 64; cc < w * 64 + 64; cc++) {
        const float* row = &fcw[(size_t)cc * C + l * 8];
        float4 fa = *(const float4*)&featL[l * 8];
        float4 fb = *(const float4*)&featL[l * 8 + 4];
        float4 wa = *(const float4*)row;
        float4 wb = *(const float4*)(row + 4);
        float s = fa.x * wa.x + fa.y * wa.y + fa.z * wa.z + fa.w * wa.w
                + fb.x * wb.x + fb.y * wb.y + fb.z * wb.z + fb.w * wb.w;
        #pragma unroll
        for (int d = 32; d >= 1; d >>= 1) s += __shfl_xor(s, d);
        if (l == 0) gamma[b * C + cc] = 1.f / (1.f + __expf(-(s + fcb[cc])));
    }
}

// ---------------------------------------------------------------------------
// out = relu(x * (1 + gamma[b,c]))
__global__ __launch_bounds__(256) void gate_kernel(const float* __restrict__ x,
                                                   const float* __restrict__ gamma,
                                                   float* __restrict__ out) {
    size_t idx = (size_t)blockIdx.x * 256 + threadIdx.x;
    int bc = (int)(idx >> 12);
    float gm = 1.f + gamma[bc];
    float4 xv = ((const float4*)x)[idx];
    float4 r;
    r.x = fmaxf(xv.x * gm, 0.f);
    r.y = fmaxf(xv.y * gm, 0.f);
    r.z = fmaxf(xv.z * gm, 0.f);
    r.w = fmaxf(xv.w * gm, 0.f);
    ((float4*)out)[idx] = r;
}

// ---------------------------------------------------------------------------
extern "C" void kernel_launch(void* const* d_in, const int* in_sizes, int n_in,
                              void* d_out, int out_size, void* d_ws, size_t ws_size,
                              hipStream_t stream) {
    const float* x      = (const float*)d_in[0];
    const float* conv_w = (const float*)d_in[1];
    const float* bn2_g  = (const float*)d_in[2];
    const float* bn2_b  = (const float*)d_in[3];
    const float* bn2_m  = (const float*)d_in[4];
    const float* bn2_v  = (const float*)d_in[5];
    const float* cw     = (const float*)d_in[6];
    const float* scale  = (const float*)d_in[7];
    const float* bn1_g  = (const float*)d_in[8];
    const float* bn1_b  = (const float*)d_in[9];
    const float* bn1_m  = (const float*)d_in[10];
    const float* bn1_v  = (const float*)d_in[11];
    const float* fcw    = (const float*)d_in[12];
    const float* fcb    = (const float*)d_in[13];
    char* wsb = (char*)d_ws;
    __bf16* zbuf  = (__bf16*)(wsb + Z_OFF);
    __bf16* wbb   = (__bf16*)(wsb + WBB_OFF);
    __bf16* cwb   = (__bf16*)(wsb + CWB_OFF);
    float*  x2    = (float*)(wsb + X2_OFF);
    float*  c2    = (float*)(wsb + C2_OFF);
    float*  asum  = (float*)(wsb + ASUM_OFF);
    float*  part  = (float*)(wsb + PART_OFF);
    float*  agg   = (float*)(wsb + AGG_OFF);
    float*  gamma = (float*)(wsb + GAMMA_OFF);
    float* out = (float*)d_out;

    prep_kernel<<<133, 256, 0, stream>>>(conv_w, cw, wbb, cwb, c2, asum);
    conv_fused_kernel<<<dim3(256, 4), 256, 0, stream>>>(
        x, wbb, bn2_g, bn2_b, bn2_m, bn2_v, zbuf, x2);
    assign_agg_kernel<<<dim3(128, 4), 256, 0, stream>>>(
        zbuf, cwb, scale, c2, x2, part, asum);
    agg_reduce_kernel<<<dim3(32, 4), 512, 0, stream>>>(part, agg);
    feat_kernel<<<4, 512, 0, stream>>>(cw, bn1_g, bn1_b, bn1_m, bn1_v,
                                       fcw, fcb, agg, asum, gamma, out);
    gate_kernel<<<32768, 256, 0, stream>>>(x, gamma, out + B * C);
}

// Round 5
// 397.817 us; speedup vs baseline: 1.6504x; 1.1542x over previous
//
#include <hip/hip_runtime.h>
#include <cstdint>

#define EPS 1e-5f
constexpr int B = 4, C = 512, HW = 16384, K = 32;

typedef __bf16 bf16x8 __attribute__((ext_vector_type(8)));
typedef float  floatx4 __attribute__((ext_vector_type(4)));
typedef unsigned int u32;

__device__ __forceinline__ void load_lds16(const void* g, void* l) {
    __builtin_amdgcn_global_load_lds((const __attribute__((address_space(1))) u32*)g,
                                     (__attribute__((address_space(3))) u32*)l,
                                     16, 0, 0);
}

// ---------------------------------------------------------------------------
// workspace byte offsets
constexpr size_t Z_OFF     = 0;            // z bf16 [b][n][c]    67,108,864
constexpr size_t WBB_OFF   = 67108864;     // W bf16 frag-swizzled   524,288
constexpr size_t CWB_OFF   = 67633152;     // cw bf16 [k][c]          32,768
constexpr size_t X2_OFF    = 67665920;     // fp32 [b*HW]            262,144
constexpr size_t C2_OFF    = 67928064;     // fp32 [K]
constexpr size_t ASUM_OFF  = 67928192;     // fp32 [B*K]
constexpr size_t PART_OFF  = 67928704;     // fp32 [B][128][K][C] 33,554,432
constexpr size_t AGG_OFF   = 101483136;    // fp32 [B][K][C]         262,144
constexpr size_t GAMMA_OFF = 101745280;    // fp32 [B][C]              8,192

// ---------------------------------------------------------------------------
// prep:
//  blocks 0..127  : conv_w fp32 -> wbb bf16 in MFMA-fragment order
//  blocks 128..131: cw fp32 -> cwb bf16 [k][c]
//  block  132     : c2[k] = ||cw_k||^2 (8 threads/k, float4, shfl-reduce);
//                   zero asum
__global__ __launch_bounds__(256) void prep_kernel(
    const float* __restrict__ conv_w, const float* __restrict__ cw,
    __bf16* __restrict__ wbb, __bf16* __restrict__ cwb,
    float* __restrict__ c2, float* __restrict__ asum) {
    const int tid = threadIdx.x, bx = blockIdx.x;
    if (bx < 128) {
        const int idx  = bx * 256 + tid;          // [0, 32768)
        const int lane = idx & 63;
        const int ks   = (idx >> 6) & 1;
        const int ii   = (idx >> 7) & 7;
        const int t    = idx >> 10;
        const float* s = conv_w + (size_t)(t * 16 + (lane & 15)) * C
                         + ii * 64 + ks * 32 + (lane >> 4) * 8;
        bf16x8 o;
        #pragma unroll
        for (int j = 0; j < 8; j++) o[j] = (__bf16)s[j];
        *(bf16x8*)&wbb[(size_t)idx * 8] = o;
    } else if (bx < 132) {
        const int idx = ((bx - 128) * 256 + tid) * 16;   // [0, 16384) elems
        const float* s = cw + idx;
        __bf16* d = cwb + idx;
        bf16x8 o0, o1;
        #pragma unroll
        for (int j = 0; j < 8; j++) o0[j] = (__bf16)s[j];
        #pragma unroll
        for (int j = 0; j < 8; j++) o1[j] = (__bf16)s[8 + j];
        *(bf16x8*)&d[0] = o0;
        *(bf16x8*)&d[8] = o1;
    } else {
        // c2: 8 threads per k (k = tid>>3 aligned within waves), float4 loads
        const int k = tid >> 3, j = tid & 7;
        const float* r = cw + k * 512 + j * 64;
        float s = 0.f;
        #pragma unroll
        for (int c4 = 0; c4 < 16; c4++) {
            float4 v = *(const float4*)&r[c4 * 4];
            s += v.x * v.x + v.y * v.y + v.z * v.z + v.w * v.w;
        }
        s += __shfl_xor(s, 1); s += __shfl_xor(s, 2); s += __shfl_xor(s, 4);
        if (j == 0) c2[k] = s;
        if (tid < 128) asum[tid] = 0.f;
    }
}

// ---------------------------------------------------------------------------
// fused conv (R1-measured version, ~117 us): transpose x in LDS + GEMM + BN +
// ReLU + x2. Raw-barrier pipeline: prefetch chunk i+1 survives the MFMA phase.
__global__ __launch_bounds__(256) void conv_fused_kernel(
    const float* __restrict__ x, const __bf16* __restrict__ wbb,
    const float* __restrict__ g2, const float* __restrict__ b2,
    const float* __restrict__ m2, const float* __restrict__ v2,
    __bf16* __restrict__ z, float* __restrict__ x2g) {
    __shared__ float  XR[2][64 * 64];   // [chunk c][n] fp32, 2x16 KB
    __shared__ __bf16 XA[64 * 72];      // [n][c-in-chunk], 9 KB
    __shared__ float  x2L[64];
    const int tid = threadIdx.x, lane = tid & 63, w = tid >> 6;
    const int l15 = lane & 15, q = lane >> 4;
    const int n0 = blockIdx.x * 64, b = blockIdx.y;
    if (tid < 64) x2L[tid] = 0.f;

    auto stage = [&](int chunk, int buf) {
        #pragma unroll
        for (int p = 0; p < 4; p++) {
            int seg = w * 4 + p;                    // 16 segs of 4 c-rows
            int cr = chunk * 64 + seg * 4 + (lane >> 4);
            const float* gp = x + ((size_t)(b * C + cr)) * HW + n0 + (lane & 15) * 4;
            load_lds16(gp, (char*)XR[buf] + seg * 1024);
        }
    };

    floatx4 acc[4][8];
    const floatx4 zv4 = {0.f, 0.f, 0.f, 0.f};
    #pragma unroll
    for (int mt = 0; mt < 4; mt++)
        #pragma unroll
        for (int ot = 0; ot < 8; ot++) acc[mt][ot] = zv4;

    stage(0, 0);
    for (int i = 0; i < 8; i++) {
        const int cur = i & 1;
        __syncthreads();                    // chunk i landed; XA free
        if (i < 7) stage(i + 1, cur ^ 1);   // prefetch survives raw barrier
        #pragma unroll
        for (int f = 0; f < 2; f++) {
            int id = f * 256 + tid;
            int n = id & 63, cs = id >> 6;
            bf16x8 o;
            #pragma unroll
            for (int j = 0; j < 8; j++) o[j] = (__bf16)XR[cur][(cs * 8 + j) * 64 + n];
            *(bf16x8*)&XA[n * 72 + cs * 8] = o;
        }
        asm volatile("s_waitcnt lgkmcnt(0)" ::: "memory");
        __builtin_amdgcn_sched_barrier(0);
        __builtin_amdgcn_s_barrier();       // XA ready; prefetch NOT drained
        __builtin_amdgcn_sched_barrier(0);
        #pragma unroll
        for (int ks = 0; ks < 2; ks++) {
            bf16x8 af[4], bfv[8];
            #pragma unroll
            for (int ot = 0; ot < 8; ot++)
                bfv[ot] = *(const bf16x8*)&wbb[
                    ((size_t)(((w * 8 + ot) * 8 + i) * 2 + ks) * 64 + lane) * 8];
            #pragma unroll
            for (int mt = 0; mt < 4; mt++)
                af[mt] = *(const bf16x8*)&XA[(mt * 16 + l15) * 72 + ks * 32 + q * 8];
            #pragma unroll
            for (int mt = 0; mt < 4; mt++)
                #pragma unroll
                for (int ot = 0; ot < 8; ot++)
                    acc[mt][ot] = __builtin_amdgcn_mfma_f32_16x16x32_bf16(
                        af[mt], bfv[ot], acc[mt][ot], 0, 0, 0);
        }
    }
    // epilogue: BN + ReLU + store z bf16 + x2 partials
    float s8[8], bi8[8];
    #pragma unroll
    for (int ot = 0; ot < 8; ot++) {
        int o = w * 128 + ot * 16 + l15;
        float s = g2[o] * rsqrtf(v2[o] + EPS);
        s8[ot] = s; bi8[ot] = b2[o] - m2[o] * s;
    }
    float xx[16];
    #pragma unroll
    for (int t = 0; t < 16; t++) xx[t] = 0.f;
    #pragma unroll
    for (int mt = 0; mt < 4; mt++)
        #pragma unroll
        for (int reg = 0; reg < 4; reg++) {
            int n = n0 + mt * 16 + q * 4 + reg;
            #pragma unroll
            for (int ot = 0; ot < 8; ot++) {
                float v = fmaxf(acc[mt][ot][reg] * s8[ot] + bi8[ot], 0.f);
                z[((size_t)(b * HW + n)) * C + w * 128 + ot * 16 + l15] = (__bf16)v;
                xx[mt * 4 + reg] += v * v;
            }
        }
    #pragma unroll
    for (int t = 0; t < 16; t++) {
        float v = xx[t];
        v += __shfl_xor(v, 1); v += __shfl_xor(v, 2);
        v += __shfl_xor(v, 4); v += __shfl_xor(v, 8);
        xx[t] = v;
    }
    if (l15 == 0) {
        #pragma unroll
        for (int mt = 0; mt < 4; mt++)
            #pragma unroll
            for (int reg = 0; reg < 4; reg++)
                atomicAdd(&x2L[mt * 16 + q * 4 + reg], xx[mt * 4 + reg]);
    }
    __syncthreads();
    if (tid < 64) x2g[(size_t)b * HW + n0 + tid] = x2L[tid];
}

// ---------------------------------------------------------------------------
// fused assign+agg (R4 version, unchanged)
__global__ __launch_bounds__(256) void assign_agg_kernel(
    const __bf16* __restrict__ zb, const __bf16* __restrict__ cwb,
    const float* __restrict__ scale, const float* __restrict__ c2,
    const float* __restrict__ x2g, float* __restrict__ part,
    float* __restrict__ asum) {
    __shared__ __bf16 ZT[32][536];   // 33.5 KB; stride 268 words -> 2-way banks
    __shared__ float  LG[32][33];    // logits [k][n]
    __shared__ __bf16 AT[32][40];    // assign [k][n]
    __shared__ float  asum_l[32];
    const int tid = threadIdx.x, lane = tid & 63, w = tid >> 6;
    const int l15 = lane & 15, q = lane >> 4;
    const int b = blockIdx.y, bx = blockIdx.x;
    if (tid < 32) asum_l[tid] = 0.f;
    float sck[8], c2k[8];
    #pragma unroll
    for (int j = 0; j < 8; j++) { sck[j] = scale[q * 8 + j]; c2k[j] = c2[q * 8 + j]; }
    const int mt_ = w >> 1, nt_ = w & 1;

    float x2r[4];
    if (w < 2) {
        #pragma unroll
        for (int s = 0; s < 4; s++)
            x2r[s] = x2g[(size_t)b * HW + bx * 128 + s * 32 + w * 16 + l15];
    }

    floatx4 agga[2][8];
    const floatx4 zv4 = {0.f, 0.f, 0.f, 0.f};
    #pragma unroll
    for (int mt = 0; mt < 2; mt++)
        #pragma unroll
        for (int ct = 0; ct < 8; ct++) agga[mt][ct] = zv4;

    bf16x8 st[8];
    #pragma unroll
    for (int p = 0; p < 8; p++) {
        int e = (p * 256 + tid) * 8;
        st[p] = *(const bf16x8*)&zb[((size_t)(b * HW + bx * 128 + (e >> 9))) * C + (e & 511)];
    }

    for (int s = 0; s < 4; s++) {
        const int nb = bx * 128 + s * 32;
        __syncthreads();   // prev agg done reading ZT; drains vm (st landed)
        #pragma unroll
        for (int p = 0; p < 8; p++) {
            int e = (p * 256 + tid) * 8;
            *(bf16x8*)&ZT[e >> 9][e & 511] = st[p];
        }
        if (s < 3) {       // prefetch next subtile; in flight across raw barriers
            #pragma unroll
            for (int p = 0; p < 8; p++) {
                int e = (p * 256 + tid) * 8;
                st[p] = *(const bf16x8*)&zb[
                    ((size_t)(b * HW + nb + 32 + (e >> 9))) * C + (e & 511)];
            }
        }
        asm volatile("s_waitcnt lgkmcnt(0)" ::: "memory");
        __builtin_amdgcn_sched_barrier(0);
        __builtin_amdgcn_s_barrier();       // ZT ready
        __builtin_amdgcn_sched_barrier(0);
        floatx4 la = zv4;
        #pragma unroll
        for (int kc = 0; kc < 16; kc++) {
            bf16x8 a  = *(const bf16x8*)&cwb[(size_t)(mt_ * 16 + l15) * C + kc * 32 + q * 8];
            bf16x8 bb = *(const bf16x8*)&ZT[nt_ * 16 + l15][kc * 32 + q * 8];
            la = __builtin_amdgcn_mfma_f32_16x16x32_bf16(a, bb, la, 0, 0, 0);
        }
        #pragma unroll
        for (int r = 0; r < 4; r++)
            LG[mt_ * 16 + q * 4 + r][nt_ * 16 + l15] = la[r];
        asm volatile("s_waitcnt lgkmcnt(0)" ::: "memory");
        __builtin_amdgcn_sched_barrier(0);
        __builtin_amdgcn_s_barrier();       // LG ready
        __builtin_amdgcn_sched_barrier(0);
        if (w < 2) {
            int nl = w * 16 + l15;
            float lg[8];
            float mx = -1e30f;
            #pragma unroll
            for (int j = 0; j < 8; j++) {
                float t = sck[j] * (x2r[s] - 2.f * LG[q * 8 + j][nl] + c2k[j]);
                lg[j] = t; mx = fmaxf(mx, t);
            }
            mx = fmaxf(mx, __shfl_xor(mx, 16));
            mx = fmaxf(mx, __shfl_xor(mx, 32));
            float se = 0.f;
            #pragma unroll
            for (int j = 0; j < 8; j++) { lg[j] = __expf(lg[j] - mx); se += lg[j]; }
            se += __shfl_xor(se, 16);
            se += __shfl_xor(se, 32);
            float inv = 1.f / se;
            #pragma unroll
            for (int j = 0; j < 8; j++) {
                float a = lg[j] * inv;
                AT[q * 8 + j][nl] = (__bf16)a;
                lg[j] = a;
            }
            #pragma unroll
            for (int j = 0; j < 8; j++) {
                float v = lg[j];
                v += __shfl_xor(v, 1); v += __shfl_xor(v, 2);
                v += __shfl_xor(v, 4); v += __shfl_xor(v, 8);
                if (l15 == 0) atomicAdd(&asum_l[q * 8 + j], v);
            }
        }
        asm volatile("s_waitcnt lgkmcnt(0)" ::: "memory");
        __builtin_amdgcn_sched_barrier(0);
        __builtin_amdgcn_s_barrier();       // AT ready
        __builtin_amdgcn_sched_barrier(0);
        bf16x8 afr0 = *(const bf16x8*)&AT[l15][q * 8];
        bf16x8 afr1 = *(const bf16x8*)&AT[16 + l15][q * 8];
        #pragma unroll
        for (int ct = 0; ct < 8; ct++) {
            int c = w * 128 + ct * 16 + l15;
            bf16x8 bb;
            #pragma unroll
            for (int j = 0; j < 8; j++) bb[j] = ZT[q * 8 + j][c];
            agga[0][ct] = __builtin_amdgcn_mfma_f32_16x16x32_bf16(afr0, bb, agga[0][ct], 0, 0, 0);
            agga[1][ct] = __builtin_amdgcn_mfma_f32_16x16x32_bf16(afr1, bb, agga[1][ct], 0, 0, 0);
        }
    }
    float* pp = part + ((size_t)(b * 128 + bx) * K) * C;
    #pragma unroll
    for (int mt = 0; mt < 2; mt++)
        #pragma unroll
        for (int ct = 0; ct < 8; ct++)
            #pragma unroll
            for (int r = 0; r < 4; r++)
                pp[(size_t)(mt * 16 + q * 4 + r) * C + w * 128 + ct * 16 + l15] =
                    agga[mt][ct][r];
    __syncthreads();
    if (tid < 32) atomicAdd(&asum[b * K + tid], asum_l[tid]);
}

// ---------------------------------------------------------------------------
// agg_reduce v2: float4 per thread, 16-deep unrolled p-loop (16 loads in
// flight) with 4 rotating accumulators. 128 blocks x 128 threads.
__global__ __launch_bounds__(128) void agg_reduce_kernel(
    const float* __restrict__ part, float* __restrict__ agg) {
    const int k = blockIdx.x, b = blockIdx.y;
    const int c = threadIdx.x * 4;
    const float* base = part + ((size_t)(b * 128) * K + k) * C + c;
    float4 s[4];
    #pragma unroll
    for (int a = 0; a < 4; a++) s[a] = {0.f, 0.f, 0.f, 0.f};
    for (int p0 = 0; p0 < 128; p0 += 16) {
        #pragma unroll
        for (int u = 0; u < 16; u++) {
            float4 v = *(const float4*)(base + (size_t)(p0 + u) * K * C);
            int a = u & 3;
            s[a].x += v.x; s[a].y += v.y; s[a].z += v.z; s[a].w += v.w;
        }
    }
    float4 r;
    r.x = (s[0].x + s[1].x) + (s[2].x + s[3].x);
    r.y = (s[0].y + s[1].y) + (s[2].y + s[3].y);
    r.z = (s[0].z + s[1].z) + (s[2].z + s[3].z);
    r.w = (s[0].w + s[1].w) + (s[2].w + s[3].w);
    *(float4*)&agg[((size_t)(b * K + k)) * C + c] = r;
}

// ---------------------------------------------------------------------------
// feat v2: grid (8 cc-groups, B). Each block redundantly recomputes the feat
// vector (cheap, L2-hot) then handles 64 gamma columns -> fc phase 8x wider.
__global__ __launch_bounds__(512) void feat_kernel(
    const float* __restrict__ cw,
    const float* __restrict__ g1, const float* __restrict__ b1,
    const float* __restrict__ m1, const float* __restrict__ v1,
    const float* __restrict__ fcw, const float* __restrict__ fcb,
    const float* __restrict__ agg, const float* __restrict__ asum,
    float* __restrict__ gamma, float* __restrict__ out_feat) {
    __shared__ float featL[C];
    const int tid = threadIdx.x;
    const int b = blockIdx.y, grp = blockIdx.x;
    float f = 0.f;
    for (int kk = 0; kk < K; kk++) {
        float s = g1[kk] * rsqrtf(v1[kk] + EPS);
        float bias = b1[kk] - m1[kk] * s;
        float e = agg[((size_t)b * K + kk) * C + tid] - asum[b * K + kk] * cw[kk * C + tid];
        f += fmaxf(e * s + bias, 0.f);
    }
    f *= (1.f / 32.f);
    if (grp == 0) out_feat[b * C + tid] = f;
    featL[tid] = f;
    __syncthreads();
    const int w = tid >> 6, l = tid & 63;
    const int cc0 = grp * 64 + w * 8;
    for (int cc = cc0; cc < cc0 + 8; cc++) {
        const float* row = &fcw[(size_t)cc * C + l * 8];
        float4 fa = *(const float4*)&featL[l * 8];
        float4 fb = *(const float4*)&featL[l * 8 + 4];
        float4 wa = *(const float4*)row;
        float4 wb = *(const float4*)(row + 4);
        float s = fa.x * wa.x + fa.y * wa.y + fa.z * wa.z + fa.w * wa.w
                + fb.x * wb.x + fb.y * wb.y + fb.z * wb.z + fb.w * wb.w;
        #pragma unroll
        for (int d = 32; d >= 1; d >>= 1) s += __shfl_xor(s, d);
        if (l == 0) gamma[b * C + cc] = 1.f / (1.f + __expf(-(s + fcb[cc])));
    }
}

// ---------------------------------------------------------------------------
// out = relu(x * (1 + gamma[b,c]))
__global__ __launch_bounds__(256) void gate_kernel(const float* __restrict__ x,
                                                   const float* __restrict__ gamma,
                                                   float* __restrict__ out) {
    size_t idx = (size_t)blockIdx.x * 256 + threadIdx.x;
    int bc = (int)(idx >> 12);
    float gm = 1.f + gamma[bc];
    float4 xv = ((const float4*)x)[idx];
    float4 r;
    r.x = fmaxf(xv.x * gm, 0.f);
    r.y = fmaxf(xv.y * gm, 0.f);
    r.z = fmaxf(xv.z * gm, 0.f);
    r.w = fmaxf(xv.w * gm, 0.f);
    ((float4*)out)[idx] = r;
}

// ---------------------------------------------------------------------------
extern "C" void kernel_launch(void* const* d_in, const int* in_sizes, int n_in,
                              void* d_out, int out_size, void* d_ws, size_t ws_size,
                              hipStream_t stream) {
    const float* x      = (const float*)d_in[0];
    const float* conv_w = (const float*)d_in[1];
    const float* bn2_g  = (const float*)d_in[2];
    const float* bn2_b  = (const float*)d_in[3];
    const float* bn2_m  = (const float*)d_in[4];
    const float* bn2_v  = (const float*)d_in[5];
    const float* cw     = (const float*)d_in[6];
    const float* scale  = (const float*)d_in[7];
    const float* bn1_g  = (const float*)d_in[8];
    const float* bn1_b  = (const float*)d_in[9];
    const float* bn1_m  = (const float*)d_in[10];
    const float* bn1_v  = (const float*)d_in[11];
    const float* fcw    = (const float*)d_in[12];
    const float* fcb    = (const float*)d_in[13];
    char* wsb = (char*)d_ws;
    __bf16* zbuf  = (__bf16*)(wsb + Z_OFF);
    __bf16* wbb   = (__bf16*)(wsb + WBB_OFF);
    __bf16* cwb   = (__bf16*)(wsb + CWB_OFF);
    float*  x2    = (float*)(wsb + X2_OFF);
    float*  c2    = (float*)(wsb + C2_OFF);
    float*  asum  = (float*)(wsb + ASUM_OFF);
    float*  part  = (float*)(wsb + PART_OFF);
    float*  agg   = (float*)(wsb + AGG_OFF);
    float*  gamma = (float*)(wsb + GAMMA_OFF);
    float* out = (float*)d_out;

    prep_kernel<<<133, 256, 0, stream>>>(conv_w, cw, wbb, cwb, c2, asum);
    conv_fused_kernel<<<dim3(256, 4), 256, 0, stream>>>(
        x, wbb, bn2_g, bn2_b, bn2_m, bn2_v, zbuf, x2);
    assign_agg_kernel<<<dim3(128, 4), 256, 0, stream>>>(
        zbuf, cwb, scale, c2, x2, part, asum);
    agg_reduce_kernel<<<dim3(32, 4), 128, 0, stream>>>(part, agg);
    feat_kernel<<<dim3(8, 4), 512, 0, stream>>>(cw, bn1_g, bn1_b, bn1_m, bn1_v,
                                                fcw, fcb, agg, asum, gamma, out);
    gate_kernel<<<32768, 256, 0, stream>>>(x, gamma, out + B * C);
}

// Round 6
// 396.257 us; speedup vs baseline: 1.6569x; 1.0039x over previous
//
#include <hip/hip_runtime.h>
#include <cstdint>

#define EPS 1e-5f
constexpr int B = 4, C = 512, HW = 16384, K = 32;

typedef __bf16 bf16x8 __attribute__((ext_vector_type(8)));
typedef float  floatx4 __attribute__((ext_vector_type(4)));
typedef unsigned int u32;

__device__ __forceinline__ void load_lds16(const void* g, void* l) {
    __builtin_amdgcn_global_load_lds((const __attribute__((address_space(1))) u32*)g,
                                     (__attribute__((address_space(3))) u32*)l,
                                     16, 0, 0);
}

// ---------------------------------------------------------------------------
// workspace byte offsets
constexpr size_t PART_OFF  = 0;            // fp32 [B][256][K][C] 67,108,864
constexpr size_t WBB_OFF   = 67108864;     // W bf16 frag-swizzled   524,288
constexpr size_t CWB_OFF   = 67633152;     // cw bf16 [k][c]          32,768
constexpr size_t AGG_OFF   = 101483136;    // fp32 [B][K][C]         262,144
constexpr size_t GAMMA_OFF = 101745280;    // fp32 [B][C]              8,192
constexpr size_t C2_OFF    = 67928064;     // fp32 [K]
constexpr size_t ASUM_OFF  = 67928192;     // fp32 [B*K]

// ---------------------------------------------------------------------------
// prep: (unchanged from R5)
__global__ __launch_bounds__(256) void prep_kernel(
    const float* __restrict__ conv_w, const float* __restrict__ cw,
    __bf16* __restrict__ wbb, __bf16* __restrict__ cwb,
    float* __restrict__ c2, float* __restrict__ asum) {
    const int tid = threadIdx.x, bx = blockIdx.x;
    if (bx < 128) {
        const int idx  = bx * 256 + tid;          // [0, 32768)
        const int lane = idx & 63;
        const int ks   = (idx >> 6) & 1;
        const int ii   = (idx >> 7) & 7;
        const int t    = idx >> 10;
        const float* s = conv_w + (size_t)(t * 16 + (lane & 15)) * C
                         + ii * 64 + ks * 32 + (lane >> 4) * 8;
        bf16x8 o;
        #pragma unroll
        for (int j = 0; j < 8; j++) o[j] = (__bf16)s[j];
        *(bf16x8*)&wbb[(size_t)idx * 8] = o;
    } else if (bx < 132) {
        const int idx = ((bx - 128) * 256 + tid) * 16;   // [0, 16384) elems
        const float* s = cw + idx;
        __bf16* d = cwb + idx;
        bf16x8 o0, o1;
        #pragma unroll
        for (int j = 0; j < 8; j++) o0[j] = (__bf16)s[j];
        #pragma unroll
        for (int j = 0; j < 8; j++) o1[j] = (__bf16)s[8 + j];
        *(bf16x8*)&d[0] = o0;
        *(bf16x8*)&d[8] = o1;
    } else {
        const int k = tid >> 3, j = tid & 7;
        const float* r = cw + k * 512 + j * 64;
        float s = 0.f;
        #pragma unroll
        for (int c4 = 0; c4 < 16; c4++) {
            float4 v = *(const float4*)&r[c4 * 4];
            s += v.x * v.x + v.y * v.y + v.z * v.z + v.w * v.w;
        }
        s += __shfl_xor(s, 1); s += __shfl_xor(s, 2); s += __shfl_xor(s, 4);
        if (j == 0) c2[k] = s;
        if (tid < 128) asum[tid] = 0.f;
    }
}

// ---------------------------------------------------------------------------
// merged conv + assign + agg. Per block: 64 n, full 512 o/c.
// Phase 1 (R1-proven conv): x transpose in LDS + GEMM + BN + ReLU -> z tile
//   kept ON-CHIP in ZT (LDS) + x2 in LDS. No z global round-trip.
// Phase 2: assign logits = cw @ z^T (MFMA, full C), softmax over k (all 4
//   waves), AT bf16.
// Phase 3: agg partials = A @ z (K-dim = 64 n) -> part[b][bx][K][C].
// LDS map (79,872 B total, 2 blocks/CU):
//   [0      , 32768) XR [2][64*64] f32   (conv)   } union
//   [32768  , 41984) XA [64*72] bf16     (conv)   } ZT [64][520] bf16 [0,66560)
//   [66560  , 74880) LG [32][65] f32
//   [74880  , 79488) AT [32][72] bf16
//   [79488  , 79744) x2L [64] f32
//   [79744  , 79872) asum_l [32] f32
__global__ __launch_bounds__(256) void conv_assign_kernel(
    const float* __restrict__ x, const __bf16* __restrict__ wbb,
    const __bf16* __restrict__ cwb,
    const float* __restrict__ g2, const float* __restrict__ b2,
    const float* __restrict__ m2, const float* __restrict__ v2,
    const float* __restrict__ scale, const float* __restrict__ c2,
    float* __restrict__ part, float* __restrict__ asum) {
    __shared__ __align__(16) char smem[79872];
    float*  XR     = (float*)smem;              // [2][4096]
    __bf16* XA     = (__bf16*)(smem + 32768);   // [64*72]
    __bf16* ZT     = (__bf16*)smem;             // [64][520]
    float*  LG     = (float*)(smem + 66560);    // [32][65]
    __bf16* AT     = (__bf16*)(smem + 74880);   // [32][72]
    float*  x2L    = (float*)(smem + 79488);    // [64]
    float*  asum_l = (float*)(smem + 79744);    // [32]

    const int tid = threadIdx.x, lane = tid & 63, w = tid >> 6;
    const int l15 = lane & 15, q = lane >> 4;
    const int bx = blockIdx.x, b = blockIdx.y;
    const int n0 = bx * 64;
    if (tid < 64) x2L[tid] = 0.f;
    if (tid < 32) asum_l[tid] = 0.f;
    float sck[8], c2k[8];
    #pragma unroll
    for (int j = 0; j < 8; j++) { sck[j] = scale[q * 8 + j]; c2k[j] = c2[q * 8 + j]; }

    auto stage = [&](int chunk, int buf) {
        #pragma unroll
        for (int p = 0; p < 4; p++) {
            int seg = w * 4 + p;                    // 16 segs of 4 c-rows
            int cr = chunk * 64 + seg * 4 + (lane >> 4);
            const float* gp = x + ((size_t)(b * C + cr)) * HW + n0 + (lane & 15) * 4;
            load_lds16(gp, (char*)XR + buf * 16384 + seg * 1024);
        }
    };

    floatx4 acc[4][8];
    const floatx4 zv4 = {0.f, 0.f, 0.f, 0.f};
    #pragma unroll
    for (int mt = 0; mt < 4; mt++)
        #pragma unroll
        for (int ot = 0; ot < 8; ot++) acc[mt][ot] = zv4;

    // ---------------- phase 1: conv GEMM (R1-proven structure) ----------------
    stage(0, 0);
    for (int i = 0; i < 8; i++) {
        const int cur = i & 1;
        __syncthreads();                    // chunk i landed; XA free
        if (i < 7) stage(i + 1, cur ^ 1);   // prefetch survives raw barrier
        #pragma unroll
        for (int f = 0; f < 2; f++) {
            int id = f * 256 + tid;
            int n = id & 63, cs = id >> 6;
            bf16x8 o;
            #pragma unroll
            for (int j = 0; j < 8; j++)
                o[j] = (__bf16)XR[cur * 4096 + (cs * 8 + j) * 64 + n];
            *(bf16x8*)&XA[n * 72 + cs * 8] = o;
        }
        asm volatile("s_waitcnt lgkmcnt(0)" ::: "memory");
        __builtin_amdgcn_sched_barrier(0);
        __builtin_amdgcn_s_barrier();       // XA ready; prefetch NOT drained
        __builtin_amdgcn_sched_barrier(0);
        #pragma unroll
        for (int ks = 0; ks < 2; ks++) {
            bf16x8 af[4], bfv[8];
            #pragma unroll
            for (int ot = 0; ot < 8; ot++)
                bfv[ot] = *(const bf16x8*)&wbb[
                    ((size_t)(((w * 8 + ot) * 8 + i) * 2 + ks) * 64 + lane) * 8];
            #pragma unroll
            for (int mt = 0; mt < 4; mt++)
                af[mt] = *(const bf16x8*)&XA[(mt * 16 + l15) * 72 + ks * 32 + q * 8];
            #pragma unroll
            for (int mt = 0; mt < 4; mt++)
                #pragma unroll
                for (int ot = 0; ot < 8; ot++)
                    acc[mt][ot] = __builtin_amdgcn_mfma_f32_16x16x32_bf16(
                        af[mt], bfv[ot], acc[mt][ot], 0, 0, 0);
        }
    }
    __syncthreads();   // all waves done with XR/XA; safe to overwrite with ZT

    // ---- BN + ReLU -> ZT (LDS) + x2 partials (identical numerics to R5) ----
    float s8[8], bi8[8];
    #pragma unroll
    for (int ot = 0; ot < 8; ot++) {
        int o = w * 128 + ot * 16 + l15;
        float s = g2[o] * rsqrtf(v2[o] + EPS);
        s8[ot] = s; bi8[ot] = b2[o] - m2[o] * s;
    }
    float xx[16];
    #pragma unroll
    for (int t = 0; t < 16; t++) xx[t] = 0.f;
    #pragma unroll
    for (int mt = 0; mt < 4; mt++)
        #pragma unroll
        for (int reg = 0; reg < 4; reg++) {
            int n = mt * 16 + q * 4 + reg;
            #pragma unroll
            for (int ot = 0; ot < 8; ot++) {
                float v = fmaxf(acc[mt][ot][reg] * s8[ot] + bi8[ot], 0.f);
                ZT[n * 520 + w * 128 + ot * 16 + l15] = (__bf16)v;
                xx[mt * 4 + reg] += v * v;
            }
        }
    #pragma unroll
    for (int t = 0; t < 16; t++) {
        float v = xx[t];
        v += __shfl_xor(v, 1); v += __shfl_xor(v, 2);
        v += __shfl_xor(v, 4); v += __shfl_xor(v, 8);
        xx[t] = v;
    }
    if (l15 == 0) {
        #pragma unroll
        for (int mt = 0; mt < 4; mt++)
            #pragma unroll
            for (int reg = 0; reg < 4; reg++)
                atomicAdd(&x2L[mt * 16 + q * 4 + reg], xx[mt * 4 + reg]);
    }
    __syncthreads();   // ZT + x2L ready

    // ---------------- phase 2: assign MFMA (full C=512) ----------------
    // wave w: k-half kh = w>>1; n-quarters nq0 = w&1 and nq0+2.
    const int kh = w >> 1, nq0 = w & 1;
    floatx4 la0 = zv4, la1 = zv4;
    #pragma unroll
    for (int kc = 0; kc < 16; kc++) {
        bf16x8 a  = *(const bf16x8*)&cwb[(size_t)(kh * 16 + l15) * C + kc * 32 + q * 8];
        bf16x8 b0 = *(const bf16x8*)&ZT[(nq0 * 16 + l15) * 520 + kc * 32 + q * 8];
        bf16x8 b1 = *(const bf16x8*)&ZT[((nq0 + 2) * 16 + l15) * 520 + kc * 32 + q * 8];
        la0 = __builtin_amdgcn_mfma_f32_16x16x32_bf16(a, b0, la0, 0, 0, 0);
        la1 = __builtin_amdgcn_mfma_f32_16x16x32_bf16(a, b1, la1, 0, 0, 0);
    }
    #pragma unroll
    for (int r = 0; r < 4; r++) {
        LG[(kh * 16 + q * 4 + r) * 65 + nq0 * 16 + l15]       = la0[r];
        LG[(kh * 16 + q * 4 + r) * 65 + (nq0 + 2) * 16 + l15] = la1[r];
    }
    __syncthreads();   // LG ready

    // ---- softmax over k: all 4 waves, each covering 16 n-columns ----
    {
        int nl = w * 16 + l15;
        float x2v = x2L[nl];
        float lg[8];
        float mx = -1e30f;
        #pragma unroll
        for (int j = 0; j < 8; j++) {
            float t = sck[j] * (x2v - 2.f * LG[(q * 8 + j) * 65 + nl] + c2k[j]);
            lg[j] = t; mx = fmaxf(mx, t);
        }
        mx = fmaxf(mx, __shfl_xor(mx, 16));
        mx = fmaxf(mx, __shfl_xor(mx, 32));
        float se = 0.f;
        #pragma unroll
        for (int j = 0; j < 8; j++) { lg[j] = __expf(lg[j] - mx); se += lg[j]; }
        se += __shfl_xor(se, 16);
        se += __shfl_xor(se, 32);
        float inv = 1.f / se;
        #pragma unroll
        for (int j = 0; j < 8; j++) {
            float a = lg[j] * inv;
            AT[(q * 8 + j) * 72 + nl] = (__bf16)a;
            lg[j] = a;
        }
        #pragma unroll
        for (int j = 0; j < 8; j++) {
            float v = lg[j];
            v += __shfl_xor(v, 1); v += __shfl_xor(v, 2);
            v += __shfl_xor(v, 4); v += __shfl_xor(v, 8);
            if (l15 == 0) atomicAdd(&asum_l[q * 8 + j], v);
        }
    }
    __syncthreads();   // AT ready

    // ---------------- phase 3: agg MFMA (K-dim = 64 n, 2 ks steps) ----------
    bf16x8 af00 = *(const bf16x8*)&AT[l15 * 72 + q * 8];
    bf16x8 af01 = *(const bf16x8*)&AT[l15 * 72 + 32 + q * 8];
    bf16x8 af10 = *(const bf16x8*)&AT[(16 + l15) * 72 + q * 8];
    bf16x8 af11 = *(const bf16x8*)&AT[(16 + l15) * 72 + 32 + q * 8];
    floatx4 agga0[8], agga1[8];
    #pragma unroll
    for (int ct = 0; ct < 8; ct++) { agga0[ct] = zv4; agga1[ct] = zv4; }
    #pragma unroll
    for (int ct = 0; ct < 8; ct++) {
        int c = w * 128 + ct * 16 + l15;
        bf16x8 b0, b1;
        #pragma unroll
        for (int j = 0; j < 8; j++) {
            b0[j] = ZT[(q * 8 + j) * 520 + c];
            b1[j] = ZT[(32 + q * 8 + j) * 520 + c];
        }
        agga0[ct] = __builtin_amdgcn_mfma_f32_16x16x32_bf16(af00, b0, agga0[ct], 0, 0, 0);
        agga0[ct] = __builtin_amdgcn_mfma_f32_16x16x32_bf16(af01, b1, agga0[ct], 0, 0, 0);
        agga1[ct] = __builtin_amdgcn_mfma_f32_16x16x32_bf16(af10, b0, agga1[ct], 0, 0, 0);
        agga1[ct] = __builtin_amdgcn_mfma_f32_16x16x32_bf16(af11, b1, agga1[ct], 0, 0, 0);
    }
    // part write: [b][bx][K][C]
    float* pp = part + ((size_t)(b * 256 + bx) * K) * C;
    #pragma unroll
    for (int ct = 0; ct < 8; ct++)
        #pragma unroll
        for (int r = 0; r < 4; r++) {
            pp[(size_t)(q * 4 + r) * C + w * 128 + ct * 16 + l15]        = agga0[ct][r];
            pp[(size_t)(16 + q * 4 + r) * C + w * 128 + ct * 16 + l15]   = agga1[ct][r];
        }
    __syncthreads();
    if (tid < 32) atomicAdd(&asum[b * K + tid], asum_l[tid]);
}

// ---------------------------------------------------------------------------
// agg_reduce: 256 partials, float4/thread, 16-deep unrolled (16 loads in
// flight) with 4 rotating accumulators. 128 blocks x 128 threads.
__global__ __launch_bounds__(128) void agg_reduce_kernel(
    const float* __restrict__ part, float* __restrict__ agg) {
    const int k = blockIdx.x, b = blockIdx.y;
    const int c = threadIdx.x * 4;
    const float* base = part + ((size_t)(b * 256) * K + k) * C + c;
    float4 s[4];
    #pragma unroll
    for (int a = 0; a < 4; a++) s[a] = {0.f, 0.f, 0.f, 0.f};
    for (int p0 = 0; p0 < 256; p0 += 16) {
        #pragma unroll
        for (int u = 0; u < 16; u++) {
            float4 v = *(const float4*)(base + (size_t)(p0 + u) * K * C);
            int a = u & 3;
            s[a].x += v.x; s[a].y += v.y; s[a].z += v.z; s[a].w += v.w;
        }
    }
    float4 r;
    r.x = (s[0].x + s[1].x) + (s[2].x + s[3].x);
    r.y = (s[0].y + s[1].y) + (s[2].y + s[3].y);
    r.z = (s[0].z + s[1].z) + (s[2].z + s[3].z);
    r.w = (s[0].w + s[1].w) + (s[2].w + s[3].w);
    *(float4*)&agg[((size_t)(b * K + k)) * C + c] = r;
}

// ---------------------------------------------------------------------------
// feat v2: grid (8 cc-groups, B). Each block redundantly recomputes the feat
// vector (cheap, L2-hot) then handles 64 gamma columns.
__global__ __launch_bounds__(512) void feat_kernel(
    const float* __restrict__ cw,
    const float* __restrict__ g1, const float* __restrict__ b1,
    const float* __restrict__ m1, const float* __restrict__ v1,
    const float* __restrict__ fcw, const float* __restrict__ fcb,
    const float* __restrict__ agg, const float* __restrict__ asum,
    float* __restrict__ gamma, float* __restrict__ out_feat) {
    __shared__ float featL[C];
    const int tid = threadIdx.x;
    const int b = blockIdx.y, grp = blockIdx.x;
    float f = 0.f;
    for (int kk = 0; kk < K; kk++) {
        float s = g1[kk] * rsqrtf(v1[kk] + EPS);
        float bias = b1[kk] - m1[kk] * s;
        float e = agg[((size_t)b * K + kk) * C + tid] - asum[b * K + kk] * cw[kk * C + tid];
        f += fmaxf(e * s + bias, 0.f);
    }
    f *= (1.f / 32.f);
    if (grp == 0) out_feat[b * C + tid] = f;
    featL[tid] = f;
    __syncthreads();
    const int w = tid >> 6, l = tid & 63;
    const int cc0 = grp * 64 + w * 8;
    for (int cc = cc0; cc < cc0 + 8; cc++) {
        const float* row = &fcw[(size_t)cc * C + l * 8];
        float4 fa = *(const float4*)&featL[l * 8];
        float4 fb = *(const float4*)&featL[l * 8 + 4];
        float4 wa = *(const float4*)row;
        float4 wb = *(const float4*)(row + 4);
        float s = fa.x * wa.x + fa.y * wa.y + fa.z * wa.z + fa.w * wa.w
                + fb.x * wb.x + fb.y * wb.y + fb.z * wb.z + fb.w * wb.w;
        #pragma unroll
        for (int d = 32; d >= 1; d >>= 1) s += __shfl_xor(s, d);
        if (l == 0) gamma[b * C + cc] = 1.f / (1.f + __expf(-(s + fcb[cc])));
    }
}

// ---------------------------------------------------------------------------
// out = relu(x * (1 + gamma[b,c]))
__global__ __launch_bounds__(256) void gate_kernel(const float* __restrict__ x,
                                                   const float* __restrict__ gamma,
                                                   float* __restrict__ out) {
    size_t idx = (size_t)blockIdx.x * 256 + threadIdx.x;
    int bc = (int)(idx >> 12);
    float gm = 1.f + gamma[bc];
    float4 xv = ((const float4*)x)[idx];
    float4 r;
    r.x = fmaxf(xv.x * gm, 0.f);
    r.y = fmaxf(xv.y * gm, 0.f);
    r.z = fmaxf(xv.z * gm, 0.f);
    r.w = fmaxf(xv.w * gm, 0.f);
    ((float4*)out)[idx] = r;
}

// ---------------------------------------------------------------------------
extern "C" void kernel_launch(void* const* d_in, const int* in_sizes, int n_in,
                              void* d_out, int out_size, void* d_ws, size_t ws_size,
                              hipStream_t stream) {
    const float* x      = (const float*)d_in[0];
    const float* conv_w = (const float*)d_in[1];
    const float* bn2_g  = (const float*)d_in[2];
    const float* bn2_b  = (const float*)d_in[3];
    const float* bn2_m  = (const float*)d_in[4];
    const float* bn2_v  = (const float*)d_in[5];
    const float* cw     = (const float*)d_in[6];
    const float* scale  = (const float*)d_in[7];
    const float* bn1_g  = (const float*)d_in[8];
    const float* bn1_b  = (const float*)d_in[9];
    const float* bn1_m  = (const float*)d_in[10];
    const float* bn1_v  = (const float*)d_in[11];
    const float* fcw    = (const float*)d_in[12];
    const float* fcb    = (const float*)d_in[13];
    char* wsb = (char*)d_ws;
    float*  part  = (float*)(wsb + PART_OFF);
    __bf16* wbb   = (__bf16*)(wsb + WBB_OFF);
    __bf16* cwb   = (__bf16*)(wsb + CWB_OFF);
    float*  c2    = (float*)(wsb + C2_OFF);
    float*  asum  = (float*)(wsb + ASUM_OFF);
    float*  agg   = (float*)(wsb + AGG_OFF);
    float*  gamma = (float*)(wsb + GAMMA_OFF);
    float* out = (float*)d_out;

    prep_kernel<<<133, 256, 0, stream>>>(conv_w, cw, wbb, cwb, c2, asum);
    conv_assign_kernel<<<dim3(256, 4), 256, 0, stream>>>(
        x, wbb, cwb, bn2_g, bn2_b, bn2_m, bn2_v, scale, c2, part, asum);
    agg_reduce_kernel<<<dim3(32, 4), 128, 0, stream>>>(part, agg);
    feat_kernel<<<dim3(8, 4), 512, 0, stream>>>(cw, bn1_g, bn1_b, bn1_m, bn1_v,
                                                fcw, fcb, agg, asum, gamma, out);
    gate_kernel<<<32768, 256, 0, stream>>>(x, gamma, out + B * C);
}